// Round 9
// baseline (411.719 us; speedup 1.0000x reference)
//
#include <hip/hip_runtime.h>

// Problem constants (CRF: B=256 seqs, M=1024 steps, D=128 feat, N=26 labels)
#define CB 256
#define CM 1024
#define CD 128
#define CN 26

typedef __attribute__((ext_vector_type(2))) float f32x2;

__device__ inline float rfl_f(float x) {
    return __int_as_float(__builtin_amdgcn_readfirstlane(__float_as_int(x)));
}
__device__ inline float rdl_f(float x, int lane) {
#if __has_builtin(__builtin_amdgcn_readlane)
    return __int_as_float(__builtin_amdgcn_readlane(__float_as_int(x), lane));
#else
    return __shfl(x, lane, 64);
#endif
}
__device__ inline float fexp2(float x) {
#if __has_builtin(__builtin_amdgcn_exp2f)
    return __builtin_amdgcn_exp2f(x);
#else
    return exp2f(x);
#endif
}
__device__ inline float flog2(float x) {
#if __has_builtin(__builtin_amdgcn_logf)
    return __builtin_amdgcn_logf(x);
#else
    return log2f(x);
#endif
}
__device__ inline f32x2 fma2(f32x2 a, f32x2 b, f32x2 c) {
#if __has_builtin(__builtin_elementwise_fma)
    return __builtin_elementwise_fma(a, b, c);  // -> v_pk_fma_f32
#else
    f32x2 r;
    r[0] = fmaf(a[0], b[0], c[0]);
    r[1] = fmaf(a[1], b[1], c[1]);
    return r;
#endif
}

// ---------------------------------------------------------------------------
// Kernel 1: emissions E[r, a] = log2(e) * dot(X[r, :], W[a, :])
//   + fused unnorm term: usum = sum_i e[i,y_i] + sum_i T[y_{i-1},y_i]
// Round-8 change: FULL-ROW X residency. Round-7 counters (VALUBusy 11.5%,
// HBM 12.8%, occupancy 40% — nothing saturated, VGPR_Count=44) showed
// per-chunk vmcnt serialization: 1-chunk-ahead ping-pong = ~416 cyc of
// compute covering ~600-900 cyc of latency, all waves stalling in lockstep.
// Fix: issue all 32 dwordx4 of the row up front (128 VGPRs, deep vmcnt
// pipeline, zero interior VMEM waits), then one pure-FMA phase with W
// streaming via s_load/K$ (wave-uniform). launch_bounds(256,2) caps the
// allocator at 256 VGPRs (~196 needed) -> 2 waves/SIMD cover the X-wait.
// ---------------------------------------------------------------------------
__global__ __launch_bounds__(256, 2) void emit_kernel(
    const float* __restrict__ X, const float* __restrict__ W,
    const int* __restrict__ labels, const float* __restrict__ T,
    float* __restrict__ E, float* __restrict__ out) {
    const int t = threadIdx.x;
    const int row = blockIdx.x * 256 + t;
    const float4* __restrict__ x4 =
        reinterpret_cast<const float4*>(X + (size_t)row * CD);

    f32x2 xr[64];  // entire 128-float row, 128 VGPRs, loads all in flight
#pragma unroll
    for (int j = 0; j < 32; ++j)
        *reinterpret_cast<float4*>(&xr[2 * j]) = x4[j];

    f32x2 acc2[CN];
#pragma unroll
    for (int a = 0; a < CN; ++a) acc2[a] = (f32x2){0.f, 0.f};

#pragma unroll
    for (int a = 0; a < CN; ++a) {
        // wave-uniform -> s_load_dwordx16 stream from K$, pipelined under FMA
        const f32x2* __restrict__ wp =
            reinterpret_cast<const f32x2*>(W + a * CD);
#pragma unroll
        for (int j = 0; j < 64; ++j) acc2[a] = fma2(xr[j], wp[j], acc2[a]);
    }

    float acc[CN];
#pragma unroll
    for (int a = 0; a < CN; ++a) acc[a] = acc2[a][0] + acc2[a][1];

    // Store E pre-scaled by log2(e): crf step then needs only exp2(e).
    const float LOG2E = 1.4426950408889634f;
    float2* e2 = reinterpret_cast<float2*>(E + (size_t)row * CN);
#pragma unroll
    for (int a = 0; a < CN / 2; ++a)
        e2[a] = make_float2(acc[2 * a] * LOG2E, acc[2 * a + 1] * LOG2E);

    // unnorm contribution of this row (natural-log units, from registers).
    int y = labels[row];
    float us = acc[0];
#pragma unroll
    for (int a = 1; a < CN; ++a) us = (y == a) ? acc[a] : us;
    if (row & (CM - 1)) {  // not a sequence start
        int yp = labels[row - 1];
        us += T[yp * CN + y];
    }
#pragma unroll
    for (int off = 32; off > 0; off >>= 1) us += __shfl_xor(us, off, 64);
    __shared__ float rsum[4];
    if ((t & 63) == 0) rsum[t >> 6] = us;
    __syncthreads();
    if (t == 0)
        atomicAdd(out, (rsum[0] + rsum[1] + rsum[2] + rsum[3]) * (1.f / CB));
}

// ---------------------------------------------------------------------------
// Kernel 2: forward/backward half-chains (round-6 math, unchanged).
// Round-8 change: 16 chains per 1024-thread block (grid 32) so each SIMD
// hosts 4 independent serial chains. Round-7 analysis: 512 one-wave blocks
// spread over 256 CUs = 1 wave/SIMD -> the ~145 cyc/step exposed latency
// (258 measured vs ~114 issue) had nothing to hide under. 4 chains/SIMD
// -> issue-bound at ~114 cyc/chain-step.
// Z = sum_a f_511[a] * beta_511[a]; interface reuses consumed E rows:
//   forward : f -> E[s][0][:],    L_f -> E[s][1][0]
//   backward: b -> E[s][1023][:], L_b -> E[s][1022][0]
// ---------------------------------------------------------------------------
template <bool BWD>
__device__ void run_half(float* __restrict__ base, const float* __restrict__ T,
                         int a, int l) {
    float AT[CN];
#pragma unroll
    for (int k = 0; k < CN; ++k)
        AT[k] = expf(BWD ? T[a * CN + k] : T[k * CN + a]);

    const int S = BWD ? -CN : CN;  // row stride (descending for backward)
    const float* __restrict__ Eb = base + (BWD ? (size_t)1023 * CN : 0) + a;

    float f, L = 0.f;
    float epf[8];
    const float* pf;
    if (BWD) {
        f = 1.f;  // beta_1023 init; first step consumes row 1023 (offset 0)
#pragma unroll
        for (int k = 0; k < 8; ++k) epf[k] = Eb[k * S];
        pf = Eb + 8 * S;
    } else {
        f = fexp2(Eb[0]);  // consumes row 0 (E in log2 units)
#pragma unroll
        for (int k = 0; k < 8; ++k) epf[k] = Eb[(1 + k) * S];
        pf = Eb + 9 * S;
    }

    auto step = [&](float e_cur, bool renorm) {
        float p = fexp2(e_cur);
        float x = BWD ? p * f : f;  // backward folds p in BEFORE broadcast
        float d0 = 0.f, d1 = 0.f, d2 = 0.f, d3 = 0.f;
#pragma unroll
        for (int b = 0; b < 24; b += 4) {
            d0 = fmaf(AT[b + 0], rdl_f(x, b + 0), d0);
            d1 = fmaf(AT[b + 1], rdl_f(x, b + 1), d1);
            d2 = fmaf(AT[b + 2], rdl_f(x, b + 2), d2);
            d3 = fmaf(AT[b + 3], rdl_f(x, b + 3), d3);
        }
        d0 = fmaf(AT[24], rdl_f(x, 24), d0);
        d1 = fmaf(AT[25], rdl_f(x, 25), d1);
        float d = (d0 + d1) + (d2 + d3);
        f = BWD ? d : p * d;
        if (renorm) {  // exact power-of-2: no rounding error
            float fr = rfl_f(f);
            int k2 = (int)((__float_as_uint(fr) >> 23) & 255) - 127;
            f = ldexpf(f, -k2);
            L += (float)k2;
        }
    };

    // Main: forward 62x8 (steps = rows 1..496), backward 63x8 (t = 0..503).
    const int NMAIN = BWD ? 63 : 62;
    for (int it = 0; it < NMAIN; ++it) {
#pragma unroll
        for (int k = 0; k < 8; ++k) {
            float e_cur = epf[k];
            epf[k] = pf[k * S];  // imm-offset loads (|k*416B| < 4 KB)
            step(e_cur, k == 7);
        }
        pf += 8 * S;
    }
    if (BWD) {
        // Tail: t = 504..511 (renorm at t=511, k==7).
#pragma unroll
        for (int k = 0; k < 8; ++k) step(epf[k], k == 7);
    } else {
        // Tail A: rows 497..504 (renorm at 504); prefetch rows 505..511.
#pragma unroll
        for (int k = 0; k < 8; ++k) {
            float e_cur = epf[k];
            if (k < 7) epf[k] = pf[k * S];
            step(e_cur, k == 7);
        }
        // Tail B: rows 505..511 (7 steps).
#pragma unroll
        for (int k = 0; k < 7; ++k) step(epf[k], false);
    }

    // Final exact renorm so stored components are O(1) and the combine
    // product f*beta cannot overflow.
    {
        float fr = rfl_f(f);
        int k2 = (int)((__float_as_uint(fr) >> 23) & 255) - 127;
        f = ldexpf(f, -k2);
        L += (float)k2;
    }

    // Store interface (cells this block alone has already consumed).
    base[(BWD ? (size_t)1023 * CN : 0) + a] = f;  // lanes>=26 dup-write a=25
    if (l == 0) base[(BWD ? (size_t)1022 * CN : (size_t)CN)] = L;
}

__global__ __launch_bounds__(1024) void crf_half_kernel(
    float* __restrict__ E, const float* __restrict__ T) {
    const int wave = threadIdx.x >> 6;             // 0..15 (wave-uniform)
    const int l = threadIdx.x & 63;
    const int chain = blockIdx.x * 16 + wave;      // 0..511
    const int s = chain >> 1;
    const int a = (l < CN) ? l : (CN - 1);
    float* base = E + (size_t)s * CM * CN;
    if (chain & 1)
        run_half<true>(base, T, a, l);
    else
        run_half<false>(base, T, a, l);
}

// ---------------------------------------------------------------------------
// Kernel 3: combine — logZ_s = ln2 * (L_f + L_b + log2(sum_a f[a]*beta[a])).
// ---------------------------------------------------------------------------
__global__ __launch_bounds__(64) void crf_combine_kernel(
    const float* __restrict__ E, float* __restrict__ out) {
    const int s = blockIdx.x;
    const int l = threadIdx.x;
    const float LN2 = 0.6931471805599453f;
    const float* base = E + (size_t)s * CM * CN;

    float v = 0.f;
    if (l < CN) v = base[l] * base[(size_t)1023 * CN + l];
#pragma unroll
    for (int off = 32; off > 0; off >>= 1) v += __shfl_xor(v, off, 64);

    if (l == 0) {
        float Lf = base[CN];
        float Lb = base[(size_t)1022 * CN];
        float logZ = LN2 * (Lf + Lb + flog2(v));
        atomicAdd(out, -logZ * (1.f / (float)CB));
    }
}

extern "C" void kernel_launch(void* const* d_in, const int* in_sizes, int n_in,
                              void* d_out, int out_size, void* d_ws,
                              size_t ws_size, hipStream_t stream) {
    const float* X = (const float*)d_in[0];   // [B, M, D]
    const int* labels = (const int*)d_in[1];  // [B, M]
    const float* W = (const float*)d_in[2];   // [N, D]
    const float* T = (const float*)d_in[3];   // [N, N]
    float* out = (float*)d_out;               // scalar
    float* E = (float*)d_ws;                  // [B*M, N] emissions (log2 units)

    hipMemsetAsync(d_out, 0, sizeof(float), stream);
    emit_kernel<<<(CB * CM) / 256, 256, 0, stream>>>(X, W, labels, T, E, out);
    crf_half_kernel<<<(CB * 2) / 16, 1024, 0, stream>>>(E, T);
    crf_combine_kernel<<<CB, 64, 0, stream>>>(E, out);
}

// Round 10
// 282.997 us; speedup vs baseline: 1.4549x; 1.4549x over previous
//
#include <hip/hip_runtime.h>

// Problem constants (CRF: B=256 seqs, M=1024 steps, D=128 feat, N=26 labels)
#define CB 256
#define CM 1024
#define CD 128
#define CN 26

__device__ inline float rfl_f(float x) {
    return __int_as_float(__builtin_amdgcn_readfirstlane(__float_as_int(x)));
}
__device__ inline float rdl_f(float x, int lane) {
#if __has_builtin(__builtin_amdgcn_readlane)
    return __int_as_float(__builtin_amdgcn_readlane(__float_as_int(x), lane));
#else
    return __shfl(x, lane, 64);
#endif
}
__device__ inline float fexp2(float x) {
#if __has_builtin(__builtin_amdgcn_exp2f)
    return __builtin_amdgcn_exp2f(x);
#else
    return exp2f(x);
#endif
}
__device__ inline float flog2(float x) {
#if __has_builtin(__builtin_amdgcn_logf)
    return __builtin_amdgcn_logf(x);
#else
    return log2f(x);
#endif
}

// ---------------------------------------------------------------------------
// Kernel 1: emissions E[r, a] = log2(e) * dot(X[r, :], W[a, :])
//   + fused unnorm term: usum = sum_i e[i,y_i] + sum_i T[y_{i-1},y_i]
// Round-10 change: R=4 rows per thread, W staged in LDS. Rationale: every
// scalar-W variant (r3-r9) sat at ~100 us, SMEM-latency-bound (SGPR budget
// blocks W prefetch depth); the r2 LDS-W variant was LDS-pipe-bound at
// R=1 (832 broadcast ds_read_b128 per wave serving only 64 rows). R=4
// amortizes the same 832 ds_reads over 256 rows -> LDS pipe ~17 us/CU,
// VALU ~11 us/CU, no SMEM or barrier in the k-loop.
// Block 256 thr x 4 rows = 1024 rows; grid 256. k-chunk = 8 floats so each
// 128B X line is touched 4x (L1/L2 absorb). Scalar acc[4][26] (~150 VGPR);
// launch_bounds(256,1) so the allocator does not squeeze (r6 spill lesson).
// ---------------------------------------------------------------------------
__global__ __launch_bounds__(256, 1) void emit_kernel(
    const float* __restrict__ X, const float* __restrict__ W,
    const int* __restrict__ labels, const float* __restrict__ T,
    float* __restrict__ E, float* __restrict__ out) {
    __shared__ float Ws[CN * CD];  // 13312 B
    __shared__ float rsum[4];

    const int t = threadIdx.x;
    const int row0 = blockIdx.x * 1024 + t * 4;

    for (int i = t; i < CN * CD; i += 256) Ws[i] = W[i];
    __syncthreads();

    float acc[4][CN];
#pragma unroll
    for (int g = 0; g < 4; ++g)
#pragma unroll
        for (int a = 0; a < CN; ++a) acc[g][a] = 0.f;

    const float4* __restrict__ x40 =
        reinterpret_cast<const float4*>(X + (size_t)row0 * CD);
    const float4* Ws4 = reinterpret_cast<const float4*>(Ws);

#pragma unroll 1
    for (int c = 0; c < 16; ++c) {  // sixteen 8-float k-chunks of D=128
        float4 xv[4][2];
#pragma unroll
        for (int g = 0; g < 4; ++g) {  // row g = 32 float4 apart
            xv[g][0] = x40[g * 32 + c * 2];
            xv[g][1] = x40[g * 32 + c * 2 + 1];
        }
#pragma unroll
        for (int a = 0; a < CN; ++a) {
            float4 w0 = Ws4[a * 32 + c * 2];      // broadcast-uniform addr
            float4 w1 = Ws4[a * 32 + c * 2 + 1];  // -> conflict-free
#pragma unroll
            for (int g = 0; g < 4; ++g) {
                float s = acc[g][a];
                s = fmaf(xv[g][0].x, w0.x, s);
                s = fmaf(xv[g][0].y, w0.y, s);
                s = fmaf(xv[g][0].z, w0.z, s);
                s = fmaf(xv[g][0].w, w0.w, s);
                s = fmaf(xv[g][1].x, w1.x, s);
                s = fmaf(xv[g][1].y, w1.y, s);
                s = fmaf(xv[g][1].z, w1.z, s);
                s = fmaf(xv[g][1].w, w1.w, s);
                acc[g][a] = s;
            }
        }
    }

    // Store E pre-scaled by log2(e): crf step then needs only exp2(e).
    const float LOG2E = 1.4426950408889634f;
#pragma unroll
    for (int g = 0; g < 4; ++g) {
        float2* e2 =
            reinterpret_cast<float2*>(E + (size_t)(row0 + g) * CN);
#pragma unroll
        for (int a = 0; a < CN / 2; ++a)
            e2[a] = make_float2(acc[g][2 * a] * LOG2E,
                                acc[g][2 * a + 1] * LOG2E);
    }

    // unnorm contribution of this thread's 4 rows (natural-log units).
    float us = 0.f;
#pragma unroll
    for (int g = 0; g < 4; ++g) {
        int row = row0 + g;
        int y = labels[row];
        float sel = acc[g][0];
#pragma unroll
        for (int a = 1; a < CN; ++a) sel = (y == a) ? acc[g][a] : sel;
        us += sel;
        if (row & (CM - 1)) {  // not a sequence start
            int yp = labels[row - 1];
            us += T[yp * CN + y];
        }
    }
#pragma unroll
    for (int off = 32; off > 0; off >>= 1) us += __shfl_xor(us, off, 64);
    if ((t & 63) == 0) rsum[t >> 6] = us;
    __syncthreads();
    if (t == 0)
        atomicAdd(out, (rsum[0] + rsum[1] + rsum[2] + rsum[3]) * (1.f / CB));
}

// ---------------------------------------------------------------------------
// Kernel 2: forward/backward half-chains — EXACT round-6/7 code (passed
// twice, ~60 us). Round-9's 16-chain packing regressed to 176 us: only 32
// CUs active and the step is issue-heavy (~206 cyc issue vs 258 latency),
// so chain co-residency cannot pay. 512 one-wave blocks is this structure's
// optimum.
// ---------------------------------------------------------------------------
template <bool BWD>
__device__ void run_half(float* __restrict__ base, const float* __restrict__ T,
                         int a, int l) {
    float AT[CN];
#pragma unroll
    for (int k = 0; k < CN; ++k)
        AT[k] = expf(BWD ? T[a * CN + k] : T[k * CN + a]);

    const int S = BWD ? -CN : CN;  // row stride (descending for backward)
    const float* __restrict__ Eb = base + (BWD ? (size_t)1023 * CN : 0) + a;

    float f, L = 0.f;
    float epf[8];
    const float* pf;
    if (BWD) {
        f = 1.f;  // beta_1023 init; first step consumes row 1023 (offset 0)
#pragma unroll
        for (int k = 0; k < 8; ++k) epf[k] = Eb[k * S];
        pf = Eb + 8 * S;
    } else {
        f = fexp2(Eb[0]);  // consumes row 0 (E in log2 units)
#pragma unroll
        for (int k = 0; k < 8; ++k) epf[k] = Eb[(1 + k) * S];
        pf = Eb + 9 * S;
    }

    auto step = [&](float e_cur, bool renorm) {
        float p = fexp2(e_cur);
        float x = BWD ? p * f : f;  // backward folds p in BEFORE broadcast
        float d0 = 0.f, d1 = 0.f, d2 = 0.f, d3 = 0.f;
#pragma unroll
        for (int b = 0; b < 24; b += 4) {
            d0 = fmaf(AT[b + 0], rdl_f(x, b + 0), d0);
            d1 = fmaf(AT[b + 1], rdl_f(x, b + 1), d1);
            d2 = fmaf(AT[b + 2], rdl_f(x, b + 2), d2);
            d3 = fmaf(AT[b + 3], rdl_f(x, b + 3), d3);
        }
        d0 = fmaf(AT[24], rdl_f(x, 24), d0);
        d1 = fmaf(AT[25], rdl_f(x, 25), d1);
        float d = (d0 + d1) + (d2 + d3);
        f = BWD ? d : p * d;
        if (renorm) {  // exact power-of-2: no rounding error
            float fr = rfl_f(f);
            int k2 = (int)((__float_as_uint(fr) >> 23) & 255) - 127;
            f = ldexpf(f, -k2);
            L += (float)k2;
        }
    };

    // Main: forward 62x8 (steps = rows 1..496), backward 63x8 (t = 0..503).
    const int NMAIN = BWD ? 63 : 62;
    for (int it = 0; it < NMAIN; ++it) {
#pragma unroll
        for (int k = 0; k < 8; ++k) {
            float e_cur = epf[k];
            epf[k] = pf[k * S];  // imm-offset loads (|k*416B| < 4 KB)
            step(e_cur, k == 7);
        }
        pf += 8 * S;
    }
    if (BWD) {
        // Tail: t = 504..511 (renorm at t=511, k==7).
#pragma unroll
        for (int k = 0; k < 8; ++k) step(epf[k], k == 7);
    } else {
        // Tail A: rows 497..504 (renorm at 504); prefetch rows 505..511.
#pragma unroll
        for (int k = 0; k < 8; ++k) {
            float e_cur = epf[k];
            if (k < 7) epf[k] = pf[k * S];
            step(e_cur, k == 7);
        }
        // Tail B: rows 505..511 (7 steps).
#pragma unroll
        for (int k = 0; k < 7; ++k) step(epf[k], false);
    }

    // Final exact renorm so stored components are O(1) and the combine
    // product f*beta cannot overflow.
    {
        float fr = rfl_f(f);
        int k2 = (int)((__float_as_uint(fr) >> 23) & 255) - 127;
        f = ldexpf(f, -k2);
        L += (float)k2;
    }

    // Store interface (cells this block alone has already consumed).
    base[(BWD ? (size_t)1023 * CN : 0) + a] = f;  // lanes>=26 dup-write a=25
    if (l == 0) base[(BWD ? (size_t)1022 * CN : (size_t)CN)] = L;
}

__global__ __launch_bounds__(64) void crf_half_kernel(
    float* __restrict__ E, const float* __restrict__ T) {
    const int s = blockIdx.x >> 1;
    const int l = threadIdx.x;
    const int a = (l < CN) ? l : (CN - 1);
    float* base = E + (size_t)s * CM * CN;
    if (blockIdx.x & 1)
        run_half<true>(base, T, a, l);
    else
        run_half<false>(base, T, a, l);
}

// ---------------------------------------------------------------------------
// Kernel 3: combine — logZ_s = ln2 * (L_f + L_b + log2(sum_a f[a]*beta[a])).
// ---------------------------------------------------------------------------
__global__ __launch_bounds__(64) void crf_combine_kernel(
    const float* __restrict__ E, float* __restrict__ out) {
    const int s = blockIdx.x;
    const int l = threadIdx.x;
    const float LN2 = 0.6931471805599453f;
    const float* base = E + (size_t)s * CM * CN;

    float v = 0.f;
    if (l < CN) v = base[l] * base[(size_t)1023 * CN + l];
#pragma unroll
    for (int off = 32; off > 0; off >>= 1) v += __shfl_xor(v, off, 64);

    if (l == 0) {
        float Lf = base[CN];
        float Lb = base[(size_t)1022 * CN];
        float logZ = LN2 * (Lf + Lb + flog2(v));
        atomicAdd(out, -logZ * (1.f / (float)CB));
    }
}

extern "C" void kernel_launch(void* const* d_in, const int* in_sizes, int n_in,
                              void* d_out, int out_size, void* d_ws,
                              size_t ws_size, hipStream_t stream) {
    const float* X = (const float*)d_in[0];   // [B, M, D]
    const int* labels = (const int*)d_in[1];  // [B, M]
    const float* W = (const float*)d_in[2];   // [N, D]
    const float* T = (const float*)d_in[3];   // [N, N]
    float* out = (float*)d_out;               // scalar
    float* E = (float*)d_ws;                  // [B*M, N] emissions (log2 units)

    hipMemsetAsync(d_out, 0, sizeof(float), stream);
    emit_kernel<<<(CB * CM) / 1024, 256, 0, stream>>>(X, W, labels, T, E, out);
    crf_half_kernel<<<CB * 2, 64, 0, stream>>>(E, T);
    crf_combine_kernel<<<CB, 64, 0, stream>>>(E, out);
}